// Round 3
// baseline (665.856 us; speedup 1.0000x reference)
//
#include <hip/hip_runtime.h>
#include <hip/hip_bf16.h>
#include <stdint.h>

#define B_    16
#define NPTS_ 20000
#define H_    128
#define O_    4
#define L_    6
#define PDIM_ 8
#define K_    3

#define TPTS 64
#define TILES_PER_B ((NPTS_ + TPTS - 1) / TPTS)    // 313

typedef __attribute__((ext_vector_type(8))) short short8;
typedef __attribute__((ext_vector_type(4))) float f32x4;
typedef __attribute__((ext_vector_type(2))) uint32_t u32x2;
typedef __attribute__((ext_vector_type(4))) uint32_t u32x4;

// X fragment layout (ushort index): [ks][pf][plane][lane][e]
// frag(ks,pf) holds k = ks*32 + (lane>>4)*8 + e , p = pf*16 + (lane&15)
#define FRAG(ks, pf, pl, lane) ((((((ks)*4 + (pf))*2 + (pl))*64) + (lane))*8)

__device__ __forceinline__ uint32_t cvt_pk_bf16(float a, float b) {
    uint32_t d;
    asm("v_cvt_pk_bf16_f32 %0, %1, %2" : "=v"(d) : "v"(a), "v"(b));
    return d;
}
__device__ __forceinline__ float bf2f(uint16_t h) {
    return __uint_as_float(((uint32_t)h) << 16);
}
__device__ __forceinline__ uint16_t f2bf(float x) {
    uint32_t u = __float_as_uint(x);
    uint32_t r = u + 0x7FFFu + ((u >> 16) & 1u);
    return (uint16_t)(r >> 16);
}

__device__ __forceinline__ float rowdy_act(float z, float a0, float a1, float a2) {
    float e  = __expf(2.f * z);
    float th = 1.f - 2.f * __builtin_amdgcn_rcpf(e + 1.f);
    float s1 = __sinf(z);
    float c1 = __cosf(z);
    float s2 = 2.f * s1 * c1;
    float s3 = s1 * (3.f - 4.f * s1 * s1);
    return th + a0 * s1 + a1 * s2 + a2 * s3;
}

// act on 4 values -> packed hi/lo bf16 dword pairs
__device__ __forceinline__ void act_pack4(const f32x4& v,
                                          const float4& A0, const float4& A1,
                                          const float4& A2, const float4& Sv,
                                          u32x2& hi, u32x2& lo) {
    float x0 = rowdy_act(v[0], A0.x, A1.x, A2.x) * Sv.x;
    float x1 = rowdy_act(v[1], A0.y, A1.y, A2.y) * Sv.y;
    float x2 = rowdy_act(v[2], A0.z, A1.z, A2.z) * Sv.z;
    float x3 = rowdy_act(v[3], A0.w, A1.w, A2.w) * Sv.w;
    uint32_t d0 = cvt_pk_bf16(x0, x1);
    uint32_t d1 = cvt_pk_bf16(x2, x3);
    float r0 = x0 - __uint_as_float(d0 << 16);
    float r1 = x1 - __uint_as_float(d0 & 0xFFFF0000u);
    float r2 = x2 - __uint_as_float(d1 << 16);
    float r3 = x3 - __uint_as_float(d1 & 0xFFFF0000u);
    hi = (u32x2){d0, d1};
    lo = (u32x2){cvt_pk_bf16(r0, r1), cvt_pk_bf16(r2, r3)};
}

// ---------- weight prep: split + A-fragment reorder ----------
// Wf layout (ushort idx): ((((layer*4 + wv)*2 + jf)*4 + ks)*64 + lane)*8 + e
// element: j = wv*32 + jf*16 + (lane&15), k = ks*32 + (lane>>4)*8 + e
__global__ void prep_w(const float* __restrict__ tWr,
                       uint16_t* __restrict__ WfH, uint16_t* __restrict__ WfL) {
    const int bid   = blockIdx.x;          // (layer, wv, jf): 5*4*2 = 40
    const int layer = bid >> 3;
    const int wv    = (bid >> 1) & 3;
    const int jf    = bid & 1;
    const int t     = threadIdx.x;         // 256 = (ks, lane)
    const int ks    = t >> 6;
    const int ln    = t & 63;
    const int j     = wv * 32 + jf * 16 + (ln & 15);
    const int kbase = ks * 32 + (ln >> 4) * 8;
    uint16_t hi[8], lo[8];
    #pragma unroll
    for (int e = 0; e < 8; ++e) {
        float w = tWr[((size_t)layer * H_ + kbase + e) * H_ + j];
        uint16_t h = f2bf(w);
        hi[e] = h;
        lo[e] = f2bf(w - bf2f(h));
    }
    size_t dst = ((size_t)((((layer * 4 + wv) * 2 + jf) * 4 + ks) * 64 + ln)) * 8;
    #pragma unroll
    for (int e = 0; e < 8; ++e) { WfH[dst + e] = hi[e]; WfL[dst + e] = lo[e]; }
}

// ---------- branch tower (tiny) ----------
__global__ void branch_kernel(
    const float* __restrict__ params,
    const float* __restrict__ bW0, const float* __restrict__ bWr,
    const float* __restrict__ bb,  const float* __restrict__ bWout,
    const float* __restrict__ bbout,
    const float* __restrict__ fW,  const float* __restrict__ fb,
    float* __restrict__ S, float* __restrict__ M, float* __restrict__ c0)
{
    const int b = blockIdx.x;
    const int j = threadIdx.x;
    __shared__ float h[H_];
    __shared__ float zl[O_][H_];

    float z = bb[j];
    #pragma unroll
    for (int k = 0; k < PDIM_; ++k)
        z = fmaf(params[b * PDIM_ + k], bW0[k * H_ + j], z);
    float hv = tanhf(z);
    float srun = hv;
    h[j] = hv;
    S[(0 * B_ + b) * H_ + j] = srun;

    for (int i = 1; i < L_; ++i) {
        __syncthreads();
        const float* W = bWr + (size_t)(i - 1) * H_ * H_;
        float zz = bb[i * H_ + j];
        for (int k = 0; k < H_; ++k)
            zz = fmaf(h[k], W[k * H_ + j], zz);
        __syncthreads();
        hv = tanhf(zz);
        h[j] = hv;
        srun += hv;
        S[(i * B_ + b) * H_ + j] = srun;
    }
    __syncthreads();

    #pragma unroll
    for (int o = 0; o < O_; ++o) {
        float acc = bbout[o * H_ + j];
        for (int k = 0; k < H_; ++k)
            acc = fmaf(h[k], bWout[(size_t)k * (H_ * O_) + o * H_ + j], acc);
        zl[o][j] = acc;
    }
    __syncthreads();

    float m[O_] = {0.f, 0.f, 0.f, 0.f};
    for (int hh = 0; hh < H_; ++hh) {
        float w = fW[j * H_ + hh];
        #pragma unroll
        for (int o = 0; o < O_; ++o)
            m[o] = fmaf(w, zl[o][hh], m[o]);
    }
    #pragma unroll
    for (int o = 0; o < O_; ++o)
        M[((size_t)b * H_ + j) * O_ + o] = m[o];

    if (j < O_) {
        float acc = 0.f;
        for (int hh = 0; hh < H_; ++hh)
            acc = fmaf(fb[hh], zl[j][hh], acc);
        c0[b * O_ + j] = acc;
    }
}

// ---------- trunk: fragment-layout LDS, conflict-free ----------
__global__ __launch_bounds__(256, 4) void trunk_mfma(
    const float* __restrict__ coords, const float* __restrict__ sdf,
    const float* __restrict__ tW0,    const float* __restrict__ tb,
    const float* __restrict__ ra,     const float* __restrict__ S,
    const float* __restrict__ M,      const float* __restrict__ c0,
    const uint16_t* __restrict__ WfH, const uint16_t* __restrict__ WfL,
    float* __restrict__ out)
{
    __shared__ __align__(16) uint16_t Xf[4 * 4 * 2 * 64 * 8];   // 32 KiB

    const int blk  = blockIdx.x;
    const int b    = blk / TILES_PER_B;
    const int tile = blk % TILES_PER_B;
    const int p0   = tile * TPTS;
    const int t    = threadIdx.x;

    // ---- layer 0: (coords,sdf) -> H, rowdy, *S0, write frag layout ----
    {
        const int p   = t >> 2;
        const int q   = t & 3;          // ks' = q, j-slab = q*32..q*32+31
        const int pf  = p >> 4;
        const int p15 = p & 15;
        int pg = p0 + p;
        int pc = pg < NPTS_ ? pg : NPTS_ - 1;
        size_t gp = (size_t)b * NPTS_ + pc;
        float in0 = coords[gp * 3 + 0], in1 = coords[gp * 3 + 1];
        float in2 = coords[gp * 3 + 2], in3 = sdf[gp];
        #pragma unroll
        for (int m = 0; m < 4; ++m) {
            const int jo = q * 32 + m * 8;
            u32x2 hiA, loA, hiB, loB;
            #pragma unroll
            for (int half = 0; half < 2; ++half) {
                const int j = jo + half * 4;
                float4 w0 = *(const float4*)(tW0 + 0 * H_ + j);
                float4 w1 = *(const float4*)(tW0 + 1 * H_ + j);
                float4 w2 = *(const float4*)(tW0 + 2 * H_ + j);
                float4 w3 = *(const float4*)(tW0 + 3 * H_ + j);
                float4 bv = *(const float4*)(tb + j);
                float4 A0 = *(const float4*)(ra + 0 * H_ + j);
                float4 A1 = *(const float4*)(ra + 1 * H_ + j);
                float4 A2 = *(const float4*)(ra + 2 * H_ + j);
                float4 Sv = *(const float4*)(S + b * H_ + j);
                f32x4 zv;
                zv[0] = fmaf(in3, w3.x, fmaf(in2, w2.x, fmaf(in1, w1.x, fmaf(in0, w0.x, bv.x))));
                zv[1] = fmaf(in3, w3.y, fmaf(in2, w2.y, fmaf(in1, w1.y, fmaf(in0, w0.y, bv.y))));
                zv[2] = fmaf(in3, w3.z, fmaf(in2, w2.z, fmaf(in1, w1.z, fmaf(in0, w0.z, bv.z))));
                zv[3] = fmaf(in3, w3.w, fmaf(in2, w2.w, fmaf(in1, w1.w, fmaf(in0, w0.w, bv.w))));
                if (half == 0) act_pack4(zv, A0, A1, A2, Sv, hiA, loA);
                else           act_pack4(zv, A0, A1, A2, Sv, hiB, loB);
            }
            const int lane = m * 16 + p15;
            *(u32x4*)(&Xf[FRAG(q, pf, 0, lane)]) = (u32x4){hiA[0], hiA[1], hiB[0], hiB[1]};
            *(u32x4*)(&Xf[FRAG(q, pf, 1, lane)]) = (u32x4){loA[0], loA[1], loB[0], loB[1]};
        }
    }
    __syncthreads();

    // ---- layers 1..5 via MFMA ----
    const int ln    = t & 63;
    const int wv    = t >> 6;          // wave -> j-slice of 32 (= ks' it produces)
    const int l15   = ln & 15;
    const int l4    = ln >> 4;
    const int jbase = wv * 32;

    for (int layer = 1; layer < L_; ++layer) {
        f32x4 acc[2][4];
        #pragma unroll
        for (int jf = 0; jf < 2; ++jf) {
            const int j = jbase + jf * 16 + l4 * 4;
            float4 bv = *(const float4*)(tb + layer * H_ + j);
            #pragma unroll
            for (int pf = 0; pf < 4; ++pf)
                acc[jf][pf] = (f32x4){bv.x, bv.y, bv.z, bv.w};
        }
        // batched A-frag loads (lane-linear, coalesced)
        const uint16_t* WHb = WfH + ((size_t)((layer - 1) * 4 + wv) * 2) * 4 * 64 * 8;
        const uint16_t* WLb = WfL + ((size_t)((layer - 1) * 4 + wv) * 2) * 4 * 64 * 8;
        short8 aH[2][4];
        #pragma unroll
        for (int jf = 0; jf < 2; ++jf)
            #pragma unroll
            for (int ks = 0; ks < 4; ++ks)
                aH[jf][ks] = *(const short8*)(WHb + ((size_t)(jf * 4 + ks) * 64 + ln) * 8);

        #pragma unroll
        for (int ks = 0; ks < 4; ++ks) {
            short8 aL0 = *(const short8*)(WLb + ((size_t)(0 * 4 + ks) * 64 + ln) * 8);
            short8 aL1 = *(const short8*)(WLb + ((size_t)(1 * 4 + ks) * 64 + ln) * 8);
            #pragma unroll
            for (int pf = 0; pf < 4; ++pf) {
                short8 bH = *(const short8*)(&Xf[FRAG(ks, pf, 0, ln)]);
                short8 bL = *(const short8*)(&Xf[FRAG(ks, pf, 1, ln)]);
                acc[0][pf] = __builtin_amdgcn_mfma_f32_16x16x32_bf16(aH[0][ks], bH, acc[0][pf], 0, 0, 0);
                acc[0][pf] = __builtin_amdgcn_mfma_f32_16x16x32_bf16(aH[0][ks], bL, acc[0][pf], 0, 0, 0);
                acc[0][pf] = __builtin_amdgcn_mfma_f32_16x16x32_bf16(aL0,       bH, acc[0][pf], 0, 0, 0);
                acc[1][pf] = __builtin_amdgcn_mfma_f32_16x16x32_bf16(aH[1][ks], bH, acc[1][pf], 0, 0, 0);
                acc[1][pf] = __builtin_amdgcn_mfma_f32_16x16x32_bf16(aH[1][ks], bL, acc[1][pf], 0, 0, 0);
                acc[1][pf] = __builtin_amdgcn_mfma_f32_16x16x32_bf16(aL1,       bH, acc[1][pf], 0, 0, 0);
            }
        }
        __syncthreads();   // all reads of Xf done

        // activation + write back into frag layout (wave's own ks'=wv slice)
        const int l4p  = l4 >> 1;
        const int eoff = (l4 & 1) * 4;
        #pragma unroll
        for (int jf = 0; jf < 2; ++jf) {
            const int j = jbase + jf * 16 + l4 * 4;
            float4 A0 = *(const float4*)(ra + (layer * K_ + 0) * H_ + j);
            float4 A1 = *(const float4*)(ra + (layer * K_ + 1) * H_ + j);
            float4 A2 = *(const float4*)(ra + (layer * K_ + 2) * H_ + j);
            float4 Sv = *(const float4*)(S + (layer * B_ + b) * H_ + j);
            const int lanep = (jf * 2 + l4p) * 16 + l15;
            #pragma unroll
            for (int pf = 0; pf < 4; ++pf) {
                u32x2 hi, lo;
                act_pack4(acc[jf][pf], A0, A1, A2, Sv, hi, lo);
                *(u32x2*)(&Xf[FRAG(wv, pf, 0, lanep) + eoff]) = hi;
                *(u32x2*)(&Xf[FRAG(wv, pf, 1, lanep) + eoff]) = lo;
            }
        }
        __syncthreads();   // writes visible
    }

    // ---- fused final layer + O-contraction ----
    {
        const int p   = t >> 2;
        const int o   = t & 3;
        const int pf  = p >> 4;
        const int p15 = p & 15;
        float acc = c0[b * O_ + o];
        const float* Mb = M + (size_t)b * H_ * O_;
        #pragma unroll
        for (int ks = 0; ks < 4; ++ks) {
            #pragma unroll
            for (int m = 0; m < 4; ++m) {
                const int lane = m * 16 + p15;
                short8 h8 = *(const short8*)(&Xf[FRAG(ks, pf, 0, lane)]);
                short8 l8 = *(const short8*)(&Xf[FRAG(ks, pf, 1, lane)]);
                const int kb = ks * 32 + m * 8;
                #pragma unroll
                for (int e = 0; e < 8; ++e) {
                    float xv = bf2f((uint16_t)h8[e]) + bf2f((uint16_t)l8[e]);
                    acc = fmaf(xv, Mb[(kb + e) * O_ + o], acc);
                }
            }
        }
        int gp = p0 + p;
        if (gp < NPTS_)
            out[((size_t)b * NPTS_ + gp) * O_ + o] = acc;
    }
}

extern "C" void kernel_launch(void* const* d_in, const int* in_sizes, int n_in,
                              void* d_out, int out_size, void* d_ws, size_t ws_size,
                              hipStream_t stream) {
    const float* coords  = (const float*)d_in[0];
    const float* sdf     = (const float*)d_in[1];
    const float* params  = (const float*)d_in[2];
    const float* bW0     = (const float*)d_in[3];
    const float* bWr     = (const float*)d_in[4];
    const float* bb      = (const float*)d_in[5];
    const float* bWout   = (const float*)d_in[6];
    const float* bbout   = (const float*)d_in[7];
    const float* tW0     = (const float*)d_in[8];
    const float* tWr     = (const float*)d_in[9];
    const float* tb      = (const float*)d_in[10];
    const float* ra      = (const float*)d_in[11];
    const float* fW      = (const float*)d_in[12];
    const float* fb      = (const float*)d_in[13];
    float* out = (float*)d_out;

    float* S  = (float*)d_ws;                          // 6*16*128 floats
    float* M  = S + (size_t)L_ * B_ * H_;              // 16*128*4
    float* c0 = M + (size_t)B_ * H_ * O_;              // 64
    uint16_t* WfH = (uint16_t*)(c0 + B_ * O_);         // 5*128*128 ushort
    uint16_t* WfL = WfH + (size_t)(L_ - 1) * H_ * H_;

    prep_w<<<dim3((L_ - 1) * 4 * 2), dim3(256), 0, stream>>>(tWr, WfH, WfL);
    branch_kernel<<<dim3(B_), dim3(H_), 0, stream>>>(
        params, bW0, bWr, bb, bWout, bbout, fW, fb, S, M, c0);
    trunk_mfma<<<dim3(B_ * TILES_PER_B), dim3(256), 0, stream>>>(
        coords, sdf, tW0, tb, ra, S, M, c0, WfH, WfL, out);
}

// Round 4
// 647.473 us; speedup vs baseline: 1.0284x; 1.0284x over previous
//
#include <hip/hip_runtime.h>
#include <hip/hip_bf16.h>
#include <stdint.h>

#define B_    16
#define NPTS_ 20000
#define H_    128
#define O_    4
#define L_    6
#define PDIM_ 8
#define K_    3

#define TPTS 64
#define TILES_PER_B ((NPTS_ + TPTS - 1) / TPTS)    // 313

typedef __attribute__((ext_vector_type(8))) short short8;
typedef __attribute__((ext_vector_type(4))) float f32x4;
typedef __attribute__((ext_vector_type(2))) uint32_t u32x2;
typedef __attribute__((ext_vector_type(4))) uint32_t u32x4;

// X fragment layout (ushort index): [ks][pf][plane][lane][e]
// frag(ks,pf) holds k = ks*32 + (lane>>4)*8 + e , p = pf*16 + (lane&15)
#define FRAG(ks, pf, pl, lane) ((((((ks)*4 + (pf))*2 + (pl))*64) + (lane))*8)
// W fragment offset within a (layer,wv) slab: (jf,ks,lane)
#define WFRAG(jf, ks, ln) (((size_t)((jf)*4 + (ks)) * 64 + (ln)) * 8)

__device__ __forceinline__ uint32_t cvt_pk_bf16(float a, float b) {
    uint32_t d;
    asm("v_cvt_pk_bf16_f32 %0, %1, %2" : "=v"(d) : "v"(a), "v"(b));
    return d;
}
__device__ __forceinline__ float bf2f(uint16_t h) {
    return __uint_as_float(((uint32_t)h) << 16);
}
__device__ __forceinline__ uint16_t f2bf(float x) {
    uint32_t u = __float_as_uint(x);
    uint32_t r = u + 0x7FFFu + ((u >> 16) & 1u);
    return (uint16_t)(r >> 16);
}

// x = S*tanh(z) + (a0*S)sin z + (2a1*S)sin z cos z + (a2*S)(3 sin z - 4 sin^3 z)
// CF planes: {S, a0*S, 2*a1*S, a2*S}; mS = -2*S hoisted by caller.
__device__ __forceinline__ float rowdy_cf(float z, float S, float mS,
                                          float A0, float A1, float A2) {
    float e, s1, c1;
    float zl = z * 2.8853900817779268f;       // 2*log2(e)
    asm("v_exp_f32 %0, %1" : "=v"(e) : "v"(zl));
    float r = __builtin_amdgcn_rcpf(e + 1.f);
    float acc = fmaf(mS, r, S);               // S*tanh(z)
    float zs = z * 0.15915494309189535f;      // 1/(2*pi)
    asm("v_sin_f32 %0, %1" : "=v"(s1) : "v"(zs));
    asm("v_cos_f32 %0, %1" : "=v"(c1) : "v"(zs));
    acc = fmaf(A0, s1, acc);
    acc = fmaf(A1, s1 * c1, acc);
    float t = s1 * s1;
    acc = fmaf(A2 * s1, fmaf(t, -4.f, 3.f), acc);
    return acc;
}

__device__ __forceinline__ void act_pack4_cf(const f32x4& v,
    const float4& S4, const float4& mS4, const float4& A0,
    const float4& A1, const float4& A2, u32x2& hi, u32x2& lo) {
    float x0 = rowdy_cf(v[0], S4.x, mS4.x, A0.x, A1.x, A2.x);
    float x1 = rowdy_cf(v[1], S4.y, mS4.y, A0.y, A1.y, A2.y);
    float x2 = rowdy_cf(v[2], S4.z, mS4.z, A0.z, A1.z, A2.z);
    float x3 = rowdy_cf(v[3], S4.w, mS4.w, A0.w, A1.w, A2.w);
    uint32_t d0 = cvt_pk_bf16(x0, x1);
    uint32_t d1 = cvt_pk_bf16(x2, x3);
    float r0 = x0 - __uint_as_float(d0 << 16);
    float r1 = x1 - __uint_as_float(d0 & 0xFFFF0000u);
    float r2 = x2 - __uint_as_float(d1 << 16);
    float r3 = x3 - __uint_as_float(d1 & 0xFFFF0000u);
    hi = (u32x2){d0, d1};
    lo = (u32x2){cvt_pk_bf16(r0, r1), cvt_pk_bf16(r2, r3)};
}

// ---------- weight prep: split + A-fragment reorder ----------
// Wf (ushort idx): ((((layer*4 + wv)*2 + jf)*4 + ks)*64 + lane)*8 + e
// element: j = wv*32 + jf*16 + (lane&15), k = ks*32 + (lane>>4)*8 + e
__global__ void prep_w(const float* __restrict__ tWr,
                       uint16_t* __restrict__ WfH, uint16_t* __restrict__ WfL) {
    const int bid   = blockIdx.x;          // (layer, wv, jf): 5*4*2 = 40
    const int layer = bid >> 3;
    const int wv    = (bid >> 1) & 3;
    const int jf    = bid & 1;
    const int t     = threadIdx.x;         // 256 = (ks, lane)
    const int ks    = t >> 6;
    const int ln    = t & 63;
    const int j     = wv * 32 + jf * 16 + (ln & 15);
    const int kbase = ks * 32 + (ln >> 4) * 8;
    uint16_t hi[8], lo[8];
    #pragma unroll
    for (int e = 0; e < 8; ++e) {
        float w = tWr[((size_t)layer * H_ + kbase + e) * H_ + j];
        uint16_t h = f2bf(w);
        hi[e] = h;
        lo[e] = f2bf(w - bf2f(h));
    }
    size_t dst = ((size_t)((((layer * 4 + wv) * 2 + jf) * 4 + ks) * 64 + ln)) * 8;
    #pragma unroll
    for (int e = 0; e < 8; ++e) { WfH[dst + e] = hi[e]; WfL[dst + e] = lo[e]; }
}

// ---------- branch tower + coefficient folding ----------
__global__ void branch_kernel(
    const float* __restrict__ params,
    const float* __restrict__ bW0, const float* __restrict__ bWr,
    const float* __restrict__ bb,  const float* __restrict__ bWout,
    const float* __restrict__ bbout,
    const float* __restrict__ fW,  const float* __restrict__ fb,
    const float* __restrict__ ra,
    float* __restrict__ CF, float* __restrict__ M, float* __restrict__ c0)
{
    const int b = blockIdx.x;
    const int j = threadIdx.x;
    __shared__ float h[H_];
    __shared__ float zl[O_][H_];

    float z = bb[j];
    #pragma unroll
    for (int k = 0; k < PDIM_; ++k)
        z = fmaf(params[b * PDIM_ + k], bW0[k * H_ + j], z);
    float hv = tanhf(z);
    float srun = hv;
    h[j] = hv;
    {
        float* cf = CF + (size_t)(0 * B_ + b) * 4 * H_;
        cf[0 * H_ + j] = srun;
        cf[1 * H_ + j] = ra[(0 * K_ + 0) * H_ + j] * srun;
        cf[2 * H_ + j] = 2.f * ra[(0 * K_ + 1) * H_ + j] * srun;
        cf[3 * H_ + j] = ra[(0 * K_ + 2) * H_ + j] * srun;
    }

    for (int i = 1; i < L_; ++i) {
        __syncthreads();
        const float* W = bWr + (size_t)(i - 1) * H_ * H_;
        float zz = bb[i * H_ + j];
        for (int k = 0; k < H_; ++k)
            zz = fmaf(h[k], W[k * H_ + j], zz);
        __syncthreads();
        hv = tanhf(zz);
        h[j] = hv;
        srun += hv;
        float* cf = CF + (size_t)(i * B_ + b) * 4 * H_;
        cf[0 * H_ + j] = srun;
        cf[1 * H_ + j] = ra[(i * K_ + 0) * H_ + j] * srun;
        cf[2 * H_ + j] = 2.f * ra[(i * K_ + 1) * H_ + j] * srun;
        cf[3 * H_ + j] = ra[(i * K_ + 2) * H_ + j] * srun;
    }
    __syncthreads();

    #pragma unroll
    for (int o = 0; o < O_; ++o) {
        float acc = bbout[o * H_ + j];
        for (int k = 0; k < H_; ++k)
            acc = fmaf(h[k], bWout[(size_t)k * (H_ * O_) + o * H_ + j], acc);
        zl[o][j] = acc;
    }
    __syncthreads();

    float m[O_] = {0.f, 0.f, 0.f, 0.f};
    for (int hh = 0; hh < H_; ++hh) {
        float w = fW[j * H_ + hh];
        #pragma unroll
        for (int o = 0; o < O_; ++o)
            m[o] = fmaf(w, zl[o][hh], m[o]);
    }
    #pragma unroll
    for (int o = 0; o < O_; ++o)
        M[((size_t)b * H_ + j) * O_ + o] = m[o];

    if (j < O_) {
        float acc = 0.f;
        for (int hh = 0; hh < H_; ++hh)
            acc = fmaf(fb[hh], zl[j][hh], acc);
        c0[b * O_ + j] = acc;
    }
}

// ---------- trunk: fragment LDS + ks-pipelined A-loads ----------
__global__ __launch_bounds__(256, 4) void trunk_mfma(
    const float* __restrict__ coords, const float* __restrict__ sdf,
    const float* __restrict__ tW0,    const float* __restrict__ tb,
    const float* __restrict__ CF,     const float* __restrict__ M,
    const float* __restrict__ c0,
    const uint16_t* __restrict__ WfH, const uint16_t* __restrict__ WfL,
    float* __restrict__ out)
{
    __shared__ __align__(16) uint16_t Xf[4 * 4 * 2 * 64 * 8];   // 32 KiB

    const int blk  = blockIdx.x;
    const int b    = blk / TILES_PER_B;
    const int tile = blk % TILES_PER_B;
    const int p0   = tile * TPTS;
    const int t    = threadIdx.x;

    // ---- layer 0: (coords,sdf) -> H, rowdy, write frag layout ----
    {
        const int p   = t >> 2;
        const int q   = t & 3;          // j-slab q -> ks'=q
        const int pf  = p >> 4;
        const int p15 = p & 15;
        int pg = p0 + p;
        int pc = pg < NPTS_ ? pg : NPTS_ - 1;
        size_t gp = (size_t)b * NPTS_ + pc;
        float in0 = coords[gp * 3 + 0], in1 = coords[gp * 3 + 1];
        float in2 = coords[gp * 3 + 2], in3 = sdf[gp];
        const float* cf0 = CF + (size_t)(0 * B_ + b) * 4 * H_;
        #pragma unroll
        for (int m = 0; m < 4; ++m) {
            const int jo = q * 32 + m * 8;
            u32x2 hiA, loA, hiB, loB;
            #pragma unroll
            for (int half = 0; half < 2; ++half) {
                const int j = jo + half * 4;
                float4 w0 = *(const float4*)(tW0 + 0 * H_ + j);
                float4 w1 = *(const float4*)(tW0 + 1 * H_ + j);
                float4 w2 = *(const float4*)(tW0 + 2 * H_ + j);
                float4 w3 = *(const float4*)(tW0 + 3 * H_ + j);
                float4 bv = *(const float4*)(tb + j);
                float4 S4 = *(const float4*)(cf0 + 0 * H_ + j);
                float4 A0 = *(const float4*)(cf0 + 1 * H_ + j);
                float4 A1 = *(const float4*)(cf0 + 2 * H_ + j);
                float4 A2 = *(const float4*)(cf0 + 3 * H_ + j);
                float4 mS4 = make_float4(-2.f * S4.x, -2.f * S4.y, -2.f * S4.z, -2.f * S4.w);
                f32x4 zv;
                zv[0] = fmaf(in3, w3.x, fmaf(in2, w2.x, fmaf(in1, w1.x, fmaf(in0, w0.x, bv.x))));
                zv[1] = fmaf(in3, w3.y, fmaf(in2, w2.y, fmaf(in1, w1.y, fmaf(in0, w0.y, bv.y))));
                zv[2] = fmaf(in3, w3.z, fmaf(in2, w2.z, fmaf(in1, w1.z, fmaf(in0, w0.z, bv.z))));
                zv[3] = fmaf(in3, w3.w, fmaf(in2, w2.w, fmaf(in1, w1.w, fmaf(in0, w0.w, bv.w))));
                if (half == 0) act_pack4_cf(zv, S4, mS4, A0, A1, A2, hiA, loA);
                else           act_pack4_cf(zv, S4, mS4, A0, A1, A2, hiB, loB);
            }
            const int lane = m * 16 + p15;
            *(u32x4*)(&Xf[FRAG(q, pf, 0, lane)]) = (u32x4){hiA[0], hiA[1], hiB[0], hiB[1]};
            *(u32x4*)(&Xf[FRAG(q, pf, 1, lane)]) = (u32x4){loA[0], loA[1], loB[0], loB[1]};
        }
    }
    __syncthreads();

    // ---- layers 1..5 via MFMA ----
    const int ln    = t & 63;
    const int wv    = t >> 6;          // wave -> j-slice of 32 (= ks' it produces)
    const int l15   = ln & 15;
    const int l4    = ln >> 4;
    const int jbase = wv * 32;

    for (int layer = 1; layer < L_; ++layer) {
        f32x4 acc0[4], acc1[4];
        {
            const int ja = jbase + 0 * 16 + l4 * 4;
            const int jb = jbase + 1 * 16 + l4 * 4;
            float4 bva = *(const float4*)(tb + layer * H_ + ja);
            float4 bvb = *(const float4*)(tb + layer * H_ + jb);
            #pragma unroll
            for (int pf = 0; pf < 4; ++pf) {
                acc0[pf] = (f32x4){bva.x, bva.y, bva.z, bva.w};
                acc1[pf] = (f32x4){bvb.x, bvb.y, bvb.z, bvb.w};
            }
        }
        const size_t wbase = ((size_t)((layer - 1) * 4 + wv)) * 4096;  // 2*4*64*8
        const uint16_t* WH = WfH + wbase;
        const uint16_t* WL = WfL + wbase;

        // pipelined A-frag loads: current(4) + next(4)
        short8 cH0 = *(const short8*)(WH + WFRAG(0, 0, ln));
        short8 cH1 = *(const short8*)(WH + WFRAG(1, 0, ln));
        short8 cL0 = *(const short8*)(WL + WFRAG(0, 0, ln));
        short8 cL1 = *(const short8*)(WL + WFRAG(1, 0, ln));
        #pragma unroll
        for (int ks = 0; ks < 4; ++ks) {
            short8 nH0, nH1, nL0, nL1;
            if (ks < 3) {
                nH0 = *(const short8*)(WH + WFRAG(0, ks + 1, ln));
                nH1 = *(const short8*)(WH + WFRAG(1, ks + 1, ln));
                nL0 = *(const short8*)(WL + WFRAG(0, ks + 1, ln));
                nL1 = *(const short8*)(WL + WFRAG(1, ks + 1, ln));
            }
            #pragma unroll
            for (int pf = 0; pf < 4; ++pf) {
                short8 bH = *(const short8*)(&Xf[FRAG(ks, pf, 0, ln)]);
                short8 bL = *(const short8*)(&Xf[FRAG(ks, pf, 1, ln)]);
                acc0[pf] = __builtin_amdgcn_mfma_f32_16x16x32_bf16(cH0, bH, acc0[pf], 0, 0, 0);
                acc0[pf] = __builtin_amdgcn_mfma_f32_16x16x32_bf16(cH0, bL, acc0[pf], 0, 0, 0);
                acc0[pf] = __builtin_amdgcn_mfma_f32_16x16x32_bf16(cL0, bH, acc0[pf], 0, 0, 0);
                acc1[pf] = __builtin_amdgcn_mfma_f32_16x16x32_bf16(cH1, bH, acc1[pf], 0, 0, 0);
                acc1[pf] = __builtin_amdgcn_mfma_f32_16x16x32_bf16(cH1, bL, acc1[pf], 0, 0, 0);
                acc1[pf] = __builtin_amdgcn_mfma_f32_16x16x32_bf16(cL1, bH, acc1[pf], 0, 0, 0);
            }
            if (ks < 3) { cH0 = nH0; cH1 = nH1; cL0 = nL0; cL1 = nL1; }
        }
        __syncthreads();   // all reads of Xf done

        // activation + write back into frag layout (wave's own ks'=wv slice)
        const int l4p  = l4 >> 1;
        const int eoff = (l4 & 1) * 4;
        const float* cf = CF + (size_t)(layer * B_ + b) * 4 * H_;
        #pragma unroll
        for (int jf = 0; jf < 2; ++jf) {
            const int j = jbase + jf * 16 + l4 * 4;
            float4 S4 = *(const float4*)(cf + 0 * H_ + j);
            float4 A0 = *(const float4*)(cf + 1 * H_ + j);
            float4 A1 = *(const float4*)(cf + 2 * H_ + j);
            float4 A2 = *(const float4*)(cf + 3 * H_ + j);
            float4 mS4 = make_float4(-2.f * S4.x, -2.f * S4.y, -2.f * S4.z, -2.f * S4.w);
            const int lanep = (jf * 2 + l4p) * 16 + l15;
            #pragma unroll
            for (int pf = 0; pf < 4; ++pf) {
                u32x2 hi, lo;
                f32x4 av = (jf == 0) ? acc0[pf] : acc1[pf];
                act_pack4_cf(av, S4, mS4, A0, A1, A2, hi, lo);
                *(u32x2*)(&Xf[FRAG(wv, pf, 0, lanep) + eoff]) = hi;
                *(u32x2*)(&Xf[FRAG(wv, pf, 1, lanep) + eoff]) = lo;
            }
        }
        __syncthreads();   // writes visible
    }

    // ---- fused final layer + O-contraction ----
    {
        const int p   = t >> 2;
        const int o   = t & 3;
        const int pf  = p >> 4;
        const int p15 = p & 15;
        float acc = c0[b * O_ + o];
        const float* Mb = M + (size_t)b * H_ * O_;
        #pragma unroll
        for (int ks = 0; ks < 4; ++ks) {
            #pragma unroll
            for (int m = 0; m < 4; ++m) {
                const int lane = m * 16 + p15;
                short8 h8 = *(const short8*)(&Xf[FRAG(ks, pf, 0, lane)]);
                short8 l8 = *(const short8*)(&Xf[FRAG(ks, pf, 1, lane)]);
                const int kb = ks * 32 + m * 8;
                #pragma unroll
                for (int e = 0; e < 8; ++e) {
                    float xv = bf2f((uint16_t)h8[e]) + bf2f((uint16_t)l8[e]);
                    acc = fmaf(xv, Mb[(kb + e) * O_ + o], acc);
                }
            }
        }
        int gp = p0 + p;
        if (gp < NPTS_)
            out[((size_t)b * NPTS_ + gp) * O_ + o] = acc;
    }
}

extern "C" void kernel_launch(void* const* d_in, const int* in_sizes, int n_in,
                              void* d_out, int out_size, void* d_ws, size_t ws_size,
                              hipStream_t stream) {
    const float* coords  = (const float*)d_in[0];
    const float* sdf     = (const float*)d_in[1];
    const float* params  = (const float*)d_in[2];
    const float* bW0     = (const float*)d_in[3];
    const float* bWr     = (const float*)d_in[4];
    const float* bb      = (const float*)d_in[5];
    const float* bWout   = (const float*)d_in[6];
    const float* bbout   = (const float*)d_in[7];
    const float* tW0     = (const float*)d_in[8];
    const float* tWr     = (const float*)d_in[9];
    const float* tb      = (const float*)d_in[10];
    const float* ra      = (const float*)d_in[11];
    const float* fW      = (const float*)d_in[12];
    const float* fb      = (const float*)d_in[13];
    float* out = (float*)d_out;

    float* CF = (float*)d_ws;                           // 6*16*4*128 = 49152 floats
    float* M  = CF + (size_t)L_ * B_ * 4 * H_;          // 16*128*4
    float* c0 = M + (size_t)B_ * H_ * O_;               // 64
    uint16_t* WfH = (uint16_t*)(c0 + B_ * O_);          // 5*128*128 ushort
    uint16_t* WfL = WfH + (size_t)(L_ - 1) * H_ * H_;

    prep_w<<<dim3((L_ - 1) * 4 * 2), dim3(256), 0, stream>>>(tWr, WfH, WfL);
    branch_kernel<<<dim3(B_), dim3(H_), 0, stream>>>(
        params, bW0, bWr, bb, bWout, bbout, fW, fb, ra, CF, M, c0);
    trunk_mfma<<<dim3(B_ * TILES_PER_B), dim3(256), 0, stream>>>(
        coords, sdf, tW0, tb, CF, M, c0, WfH, WfL, out);
}

// Round 5
// 621.210 us; speedup vs baseline: 1.0719x; 1.0423x over previous
//
#include <hip/hip_runtime.h>
#include <hip/hip_bf16.h>
#include <stdint.h>

#define B_    16
#define NPTS_ 20000
#define H_    128
#define O_    4
#define L_    6
#define PDIM_ 8
#define K_    3

#define TPTS 64
#define TILES_PER_B ((NPTS_ + TPTS - 1) / TPTS)    // 313

typedef __attribute__((ext_vector_type(8))) short short8;
typedef __attribute__((ext_vector_type(4))) float f32x4;
typedef __attribute__((ext_vector_type(2))) uint32_t u32x2;
typedef __attribute__((ext_vector_type(4))) uint32_t u32x4;

// X fragment layout (ushort index): [ks][pf][plane][lane][e]
// frag(ks,pf) holds k = ks*32 + (lane>>4)*8 + e , p = pf*16 + (lane&15)
#define FRAG(ks, pf, pl, lane) ((((((ks)*4 + (pf))*2 + (pl))*64) + (lane))*8)
// W fragment offset within a (layer,wv) slab: (jf,ks,lane)
#define WFRAG(jf, ks, ln) (((size_t)((jf)*4 + (ks)) * 64 + (ln)) * 8)

__device__ __forceinline__ uint32_t cvt_pk_bf16(float a, float b) {
    uint32_t d;
    asm("v_cvt_pk_bf16_f32 %0, %1, %2" : "=v"(d) : "v"(a), "v"(b));
    return d;
}
__device__ __forceinline__ float bf2f(uint16_t h) {
    return __uint_as_float(((uint32_t)h) << 16);
}
__device__ __forceinline__ uint16_t f2bf(float x) {
    uint32_t u = __float_as_uint(x);
    uint32_t r = u + 0x7FFFu + ((u >> 16) & 1u);
    return (uint16_t)(r >> 16);
}

// x = S*tanh(z) + (a0*S)sin z + (2a1*S)sin z cos z + (a2*S)(3 sin z - 4 sin^3 z)
// CF planes: {S, a0*S, 2*a1*S, a2*S}; mS = -2*S hoisted by caller.
__device__ __forceinline__ float rowdy_cf(float z, float S, float mS,
                                          float A0, float A1, float A2) {
    float e, s1, c1;
    float zl = z * 2.8853900817779268f;       // 2*log2(e)
    asm("v_exp_f32 %0, %1" : "=v"(e) : "v"(zl));
    float r = __builtin_amdgcn_rcpf(e + 1.f);
    float acc = fmaf(mS, r, S);               // S*tanh(z)
    float zs = z * 0.15915494309189535f;      // 1/(2*pi)
    asm("v_sin_f32 %0, %1" : "=v"(s1) : "v"(zs));
    asm("v_cos_f32 %0, %1" : "=v"(c1) : "v"(zs));
    acc = fmaf(A0, s1, acc);
    acc = fmaf(A1, s1 * c1, acc);
    float t = s1 * s1;
    acc = fmaf(A2 * s1, fmaf(t, -4.f, 3.f), acc);
    return acc;
}

__device__ __forceinline__ void act_pack4_cf(const f32x4& v,
    const float4& S4, const float4& mS4, const float4& A0,
    const float4& A1, const float4& A2, u32x2& hi, u32x2& lo) {
    float x0 = rowdy_cf(v[0], S4.x, mS4.x, A0.x, A1.x, A2.x);
    float x1 = rowdy_cf(v[1], S4.y, mS4.y, A0.y, A1.y, A2.y);
    float x2 = rowdy_cf(v[2], S4.z, mS4.z, A0.z, A1.z, A2.z);
    float x3 = rowdy_cf(v[3], S4.w, mS4.w, A0.w, A1.w, A2.w);
    uint32_t d0 = cvt_pk_bf16(x0, x1);
    uint32_t d1 = cvt_pk_bf16(x2, x3);
    float r0 = x0 - __uint_as_float(d0 << 16);
    float r1 = x1 - __uint_as_float(d0 & 0xFFFF0000u);
    float r2 = x2 - __uint_as_float(d1 << 16);
    float r3 = x3 - __uint_as_float(d1 & 0xFFFF0000u);
    hi = (u32x2){d0, d1};
    lo = (u32x2){cvt_pk_bf16(r0, r1), cvt_pk_bf16(r2, r3)};
}

// ---------- weight prep: split + A-fragment reorder ----------
// Wf (ushort idx): ((((layer*4 + wv)*2 + jf)*4 + ks)*64 + lane)*8 + e
// element: j = wv*32 + jf*16 + (lane&15), k = ks*32 + (lane>>4)*8 + e
__global__ void prep_w(const float* __restrict__ tWr,
                       uint16_t* __restrict__ WfH, uint16_t* __restrict__ WfL) {
    const int bid   = blockIdx.x;          // (layer, wv, jf): 5*4*2 = 40
    const int layer = bid >> 3;
    const int wv    = (bid >> 1) & 3;
    const int jf    = bid & 1;
    const int t     = threadIdx.x;         // 256 = (ks, lane)
    const int ks    = t >> 6;
    const int ln    = t & 63;
    const int j     = wv * 32 + jf * 16 + (ln & 15);
    const int kbase = ks * 32 + (ln >> 4) * 8;
    uint16_t hi[8], lo[8];
    #pragma unroll
    for (int e = 0; e < 8; ++e) {
        float w = tWr[((size_t)layer * H_ + kbase + e) * H_ + j];
        uint16_t h = f2bf(w);
        hi[e] = h;
        lo[e] = f2bf(w - bf2f(h));
    }
    size_t dst = ((size_t)((((layer * 4 + wv) * 2 + jf) * 4 + ks) * 64 + ln)) * 8;
    #pragma unroll
    for (int e = 0; e < 8; ++e) { WfH[dst + e] = hi[e]; WfL[dst + e] = lo[e]; }
}

// ---------- branch tower + coefficient folding ----------
__global__ void branch_kernel(
    const float* __restrict__ params,
    const float* __restrict__ bW0, const float* __restrict__ bWr,
    const float* __restrict__ bb,  const float* __restrict__ bWout,
    const float* __restrict__ bbout,
    const float* __restrict__ fW,  const float* __restrict__ fb,
    const float* __restrict__ ra,
    float* __restrict__ CF, float* __restrict__ M, float* __restrict__ c0)
{
    const int b = blockIdx.x;
    const int j = threadIdx.x;
    __shared__ float h[H_];
    __shared__ float zl[O_][H_];

    float z = bb[j];
    #pragma unroll
    for (int k = 0; k < PDIM_; ++k)
        z = fmaf(params[b * PDIM_ + k], bW0[k * H_ + j], z);
    float hv = tanhf(z);
    float srun = hv;
    h[j] = hv;
    {
        float* cf = CF + (size_t)(0 * B_ + b) * 4 * H_;
        cf[0 * H_ + j] = srun;
        cf[1 * H_ + j] = ra[(0 * K_ + 0) * H_ + j] * srun;
        cf[2 * H_ + j] = 2.f * ra[(0 * K_ + 1) * H_ + j] * srun;
        cf[3 * H_ + j] = ra[(0 * K_ + 2) * H_ + j] * srun;
    }

    for (int i = 1; i < L_; ++i) {
        __syncthreads();
        const float* W = bWr + (size_t)(i - 1) * H_ * H_;
        float zz = bb[i * H_ + j];
        for (int k = 0; k < H_; ++k)
            zz = fmaf(h[k], W[k * H_ + j], zz);
        __syncthreads();
        hv = tanhf(zz);
        h[j] = hv;
        srun += hv;
        float* cf = CF + (size_t)(i * B_ + b) * 4 * H_;
        cf[0 * H_ + j] = srun;
        cf[1 * H_ + j] = ra[(i * K_ + 0) * H_ + j] * srun;
        cf[2 * H_ + j] = 2.f * ra[(i * K_ + 1) * H_ + j] * srun;
        cf[3 * H_ + j] = ra[(i * K_ + 2) * H_ + j] * srun;
    }
    __syncthreads();

    #pragma unroll
    for (int o = 0; o < O_; ++o) {
        float acc = bbout[o * H_ + j];
        for (int k = 0; k < H_; ++k)
            acc = fmaf(h[k], bWout[(size_t)k * (H_ * O_) + o * H_ + j], acc);
        zl[o][j] = acc;
    }
    __syncthreads();

    float m[O_] = {0.f, 0.f, 0.f, 0.f};
    for (int hh = 0; hh < H_; ++hh) {
        float w = fW[j * H_ + hh];
        #pragma unroll
        for (int o = 0; o < O_; ++o)
            m[o] = fmaf(w, zl[o][hh], m[o]);
    }
    #pragma unroll
    for (int o = 0; o < O_; ++o)
        M[((size_t)b * H_ + j) * O_ + o] = m[o];

    if (j < O_) {
        float acc = 0.f;
        for (int hh = 0; hh < H_; ++hh)
            acc = fmaf(fb[hh], zl[j][hh], acc);
        c0[b * O_ + j] = acc;
    }
}

// ---------- trunk: fragment LDS + ks-pipelined A-loads ----------
// launch_bounds(256,3): VGPR cap ~170 (512-reg SIMD pool / 3 waves).
// (256,4) capped at 128 and spilled the accumulators -> 1.4 GB/dispatch
// scratch traffic (R3/R4 FETCH+WRITE counters).
__global__ __launch_bounds__(256, 3) void trunk_mfma(
    const float* __restrict__ coords, const float* __restrict__ sdf,
    const float* __restrict__ tW0,    const float* __restrict__ tb,
    const float* __restrict__ CF,     const float* __restrict__ M,
    const float* __restrict__ c0,
    const uint16_t* __restrict__ WfH, const uint16_t* __restrict__ WfL,
    float* __restrict__ out)
{
    __shared__ __align__(16) uint16_t Xf[4 * 4 * 2 * 64 * 8];   // 32 KiB

    const int blk  = blockIdx.x;
    const int b    = blk / TILES_PER_B;
    const int tile = blk % TILES_PER_B;
    const int p0   = tile * TPTS;
    const int t    = threadIdx.x;

    // ---- layer 0: (coords,sdf) -> H, rowdy, write frag layout ----
    {
        const int p   = t >> 2;
        const int q   = t & 3;          // j-slab q -> ks'=q
        const int pf  = p >> 4;
        const int p15 = p & 15;
        int pg = p0 + p;
        int pc = pg < NPTS_ ? pg : NPTS_ - 1;
        size_t gp = (size_t)b * NPTS_ + pc;
        float in0 = coords[gp * 3 + 0], in1 = coords[gp * 3 + 1];
        float in2 = coords[gp * 3 + 2], in3 = sdf[gp];
        const float* cf0 = CF + (size_t)(0 * B_ + b) * 4 * H_;
        #pragma unroll
        for (int m = 0; m < 4; ++m) {
            const int jo = q * 32 + m * 8;
            u32x2 hiA, loA, hiB, loB;
            #pragma unroll
            for (int half = 0; half < 2; ++half) {
                const int j = jo + half * 4;
                float4 w0 = *(const float4*)(tW0 + 0 * H_ + j);
                float4 w1 = *(const float4*)(tW0 + 1 * H_ + j);
                float4 w2 = *(const float4*)(tW0 + 2 * H_ + j);
                float4 w3 = *(const float4*)(tW0 + 3 * H_ + j);
                float4 bv = *(const float4*)(tb + j);
                float4 S4 = *(const float4*)(cf0 + 0 * H_ + j);
                float4 A0 = *(const float4*)(cf0 + 1 * H_ + j);
                float4 A1 = *(const float4*)(cf0 + 2 * H_ + j);
                float4 A2 = *(const float4*)(cf0 + 3 * H_ + j);
                float4 mS4 = make_float4(-2.f * S4.x, -2.f * S4.y, -2.f * S4.z, -2.f * S4.w);
                f32x4 zv;
                zv[0] = fmaf(in3, w3.x, fmaf(in2, w2.x, fmaf(in1, w1.x, fmaf(in0, w0.x, bv.x))));
                zv[1] = fmaf(in3, w3.y, fmaf(in2, w2.y, fmaf(in1, w1.y, fmaf(in0, w0.y, bv.y))));
                zv[2] = fmaf(in3, w3.z, fmaf(in2, w2.z, fmaf(in1, w1.z, fmaf(in0, w0.z, bv.z))));
                zv[3] = fmaf(in3, w3.w, fmaf(in2, w2.w, fmaf(in1, w1.w, fmaf(in0, w0.w, bv.w))));
                if (half == 0) act_pack4_cf(zv, S4, mS4, A0, A1, A2, hiA, loA);
                else           act_pack4_cf(zv, S4, mS4, A0, A1, A2, hiB, loB);
            }
            const int lane = m * 16 + p15;
            *(u32x4*)(&Xf[FRAG(q, pf, 0, lane)]) = (u32x4){hiA[0], hiA[1], hiB[0], hiB[1]};
            *(u32x4*)(&Xf[FRAG(q, pf, 1, lane)]) = (u32x4){loA[0], loA[1], loB[0], loB[1]};
        }
    }
    __syncthreads();

    // ---- layers 1..5 via MFMA ----
    const int ln    = t & 63;
    const int wv    = t >> 6;          // wave -> j-slice of 32 (= ks' it produces)
    const int l15   = ln & 15;
    const int l4    = ln >> 4;
    const int jbase = wv * 32;

    for (int layer = 1; layer < L_; ++layer) {
        f32x4 acc0[4], acc1[4];
        {
            const int ja = jbase + 0 * 16 + l4 * 4;
            const int jb = jbase + 1 * 16 + l4 * 4;
            float4 bva = *(const float4*)(tb + layer * H_ + ja);
            float4 bvb = *(const float4*)(tb + layer * H_ + jb);
            #pragma unroll
            for (int pf = 0; pf < 4; ++pf) {
                acc0[pf] = (f32x4){bva.x, bva.y, bva.z, bva.w};
                acc1[pf] = (f32x4){bvb.x, bvb.y, bvb.z, bvb.w};
            }
        }
        const size_t wbase = ((size_t)((layer - 1) * 4 + wv)) * 4096;  // 2*4*64*8
        const uint16_t* WH = WfH + wbase;
        const uint16_t* WL = WfL + wbase;

        // pipelined A-frag loads: current(4) + next(4)
        short8 cH0 = *(const short8*)(WH + WFRAG(0, 0, ln));
        short8 cH1 = *(const short8*)(WH + WFRAG(1, 0, ln));
        short8 cL0 = *(const short8*)(WL + WFRAG(0, 0, ln));
        short8 cL1 = *(const short8*)(WL + WFRAG(1, 0, ln));
        #pragma unroll
        for (int ks = 0; ks < 4; ++ks) {
            short8 nH0, nH1, nL0, nL1;
            if (ks < 3) {
                nH0 = *(const short8*)(WH + WFRAG(0, ks + 1, ln));
                nH1 = *(const short8*)(WH + WFRAG(1, ks + 1, ln));
                nL0 = *(const short8*)(WL + WFRAG(0, ks + 1, ln));
                nL1 = *(const short8*)(WL + WFRAG(1, ks + 1, ln));
            }
            #pragma unroll
            for (int pf = 0; pf < 4; ++pf) {
                short8 bH = *(const short8*)(&Xf[FRAG(ks, pf, 0, ln)]);
                short8 bL = *(const short8*)(&Xf[FRAG(ks, pf, 1, ln)]);
                acc0[pf] = __builtin_amdgcn_mfma_f32_16x16x32_bf16(cH0, bH, acc0[pf], 0, 0, 0);
                acc0[pf] = __builtin_amdgcn_mfma_f32_16x16x32_bf16(cH0, bL, acc0[pf], 0, 0, 0);
                acc0[pf] = __builtin_amdgcn_mfma_f32_16x16x32_bf16(cL0, bH, acc0[pf], 0, 0, 0);
                acc1[pf] = __builtin_amdgcn_mfma_f32_16x16x32_bf16(cH1, bH, acc1[pf], 0, 0, 0);
                acc1[pf] = __builtin_amdgcn_mfma_f32_16x16x32_bf16(cH1, bL, acc1[pf], 0, 0, 0);
                acc1[pf] = __builtin_amdgcn_mfma_f32_16x16x32_bf16(cL1, bH, acc1[pf], 0, 0, 0);
            }
            if (ks < 3) { cH0 = nH0; cH1 = nH1; cL0 = nL0; cL1 = nL1; }
        }
        __syncthreads();   // all reads of Xf done

        // activation + write back into frag layout (wave's own ks'=wv slice)
        const int l4p  = l4 >> 1;
        const int eoff = (l4 & 1) * 4;
        const float* cf = CF + (size_t)(layer * B_ + b) * 4 * H_;
        #pragma unroll
        for (int jf = 0; jf < 2; ++jf) {
            const int j = jbase + jf * 16 + l4 * 4;
            float4 S4 = *(const float4*)(cf + 0 * H_ + j);
            float4 A0 = *(const float4*)(cf + 1 * H_ + j);
            float4 A1 = *(const float4*)(cf + 2 * H_ + j);
            float4 A2 = *(const float4*)(cf + 3 * H_ + j);
            float4 mS4 = make_float4(-2.f * S4.x, -2.f * S4.y, -2.f * S4.z, -2.f * S4.w);
            const int lanep = (jf * 2 + l4p) * 16 + l15;
            #pragma unroll
            for (int pf = 0; pf < 4; ++pf) {
                u32x2 hi, lo;
                f32x4 av = (jf == 0) ? acc0[pf] : acc1[pf];
                act_pack4_cf(av, S4, mS4, A0, A1, A2, hi, lo);
                *(u32x2*)(&Xf[FRAG(wv, pf, 0, lanep) + eoff]) = hi;
                *(u32x2*)(&Xf[FRAG(wv, pf, 1, lanep) + eoff]) = lo;
            }
        }
        __syncthreads();   // writes visible
    }

    // ---- fused final layer + O-contraction ----
    {
        const int p   = t >> 2;
        const int o   = t & 3;
        const int pf  = p >> 4;
        const int p15 = p & 15;
        float acc = c0[b * O_ + o];
        const float* Mb = M + (size_t)b * H_ * O_;
        #pragma unroll
        for (int ks = 0; ks < 4; ++ks) {
            #pragma unroll
            for (int m = 0; m < 4; ++m) {
                const int lane = m * 16 + p15;
                short8 h8 = *(const short8*)(&Xf[FRAG(ks, pf, 0, lane)]);
                short8 l8 = *(const short8*)(&Xf[FRAG(ks, pf, 1, lane)]);
                const int kb = ks * 32 + m * 8;
                #pragma unroll
                for (int e = 0; e < 8; ++e) {
                    float xv = bf2f((uint16_t)h8[e]) + bf2f((uint16_t)l8[e]);
                    acc = fmaf(xv, Mb[(kb + e) * O_ + o], acc);
                }
            }
        }
        int gp = p0 + p;
        if (gp < NPTS_)
            out[((size_t)b * NPTS_ + gp) * O_ + o] = acc;
    }
}

extern "C" void kernel_launch(void* const* d_in, const int* in_sizes, int n_in,
                              void* d_out, int out_size, void* d_ws, size_t ws_size,
                              hipStream_t stream) {
    const float* coords  = (const float*)d_in[0];
    const float* sdf     = (const float*)d_in[1];
    const float* params  = (const float*)d_in[2];
    const float* bW0     = (const float*)d_in[3];
    const float* bWr     = (const float*)d_in[4];
    const float* bb      = (const float*)d_in[5];
    const float* bWout   = (const float*)d_in[6];
    const float* bbout   = (const float*)d_in[7];
    const float* tW0     = (const float*)d_in[8];
    const float* tWr     = (const float*)d_in[9];
    const float* tb      = (const float*)d_in[10];
    const float* ra      = (const float*)d_in[11];
    const float* fW      = (const float*)d_in[12];
    const float* fb      = (const float*)d_in[13];
    float* out = (float*)d_out;

    float* CF = (float*)d_ws;                           // 6*16*4*128 = 49152 floats
    float* M  = CF + (size_t)L_ * B_ * 4 * H_;          // 16*128*4
    float* c0 = M + (size_t)B_ * H_ * O_;               // 64
    uint16_t* WfH = (uint16_t*)(c0 + B_ * O_);          // 5*128*128 ushort
    uint16_t* WfL = WfH + (size_t)(L_ - 1) * H_ * H_;

    prep_w<<<dim3((L_ - 1) * 4 * 2), dim3(256), 0, stream>>>(tWr, WfH, WfL);
    branch_kernel<<<dim3(B_), dim3(H_), 0, stream>>>(
        params, bW0, bWr, bb, bWout, bbout, fW, fb, ra, CF, M, c0);
    trunk_mfma<<<dim3(B_ * TILES_PER_B), dim3(256), 0, stream>>>(
        coords, sdf, tW0, tb, CF, M, c0, WfH, WfL, out);
}

// Round 7
// 487.348 us; speedup vs baseline: 1.3663x; 1.2747x over previous
//
#include <hip/hip_runtime.h>
#include <hip/hip_bf16.h>
#include <stdint.h>

#define B_    16
#define NPTS_ 20000
#define H_    128
#define O_    4
#define L_    6
#define PDIM_ 8
#define K_    3

#define TPTS 64
#define TILES_PER_B ((NPTS_ + TPTS - 1) / TPTS)    // 313

typedef __attribute__((ext_vector_type(8))) short short8;
typedef __attribute__((ext_vector_type(4))) float f32x4;
typedef __attribute__((ext_vector_type(2))) uint32_t u32x2;
typedef __attribute__((ext_vector_type(4))) uint32_t u32x4;

// X fragment layout (ushort index within one buffer): [ks][pf][plane][lane][e]
// frag(ks,pf) holds k = ks*32 + (lane>>4)*8 + e , p = pf*16 + (lane&15)
#define FRAG(ks, pf, pl, lane) ((((((ks)*4 + (pf))*2 + (pl))*64) + (lane))*8)
// W fragment offset within a (layer,wv) slab: (jf,ks,lane)
#define WFRAG(jf, ks, ln) (((size_t)((jf)*4 + (ks)) * 64 + (ln)) * 8)

__device__ __forceinline__ uint32_t cvt_pk_bf16(float a, float b) {
    uint32_t d;
    asm("v_cvt_pk_bf16_f32 %0, %1, %2" : "=v"(d) : "v"(a), "v"(b));
    return d;
}
__device__ __forceinline__ float bf2f(uint16_t h) {
    return __uint_as_float(((uint32_t)h) << 16);
}
__device__ __forceinline__ uint16_t f2bf(float x) {
    uint32_t u = __float_as_uint(x);
    uint32_t r = u + 0x7FFFu + ((u >> 16) & 1u);
    return (uint16_t)(r >> 16);
}

// x = S*tanh(z) + (a0*S)sin z + (2a1*S)sin z cos z + (a2*S)(3 sin z - 4 sin^3 z)
// CF planes: {S, a0*S, 2*a1*S, a2*S}; mS = -2*S hoisted by caller.
__device__ __forceinline__ float rowdy_cf(float z, float S, float mS,
                                          float A0, float A1, float A2) {
    float e, s1, c1;
    float zl = z * 2.8853900817779268f;       // 2*log2(e)
    asm("v_exp_f32 %0, %1" : "=v"(e) : "v"(zl));
    float r = __builtin_amdgcn_rcpf(e + 1.f);
    float acc = fmaf(mS, r, S);               // S*tanh(z)
    float zs = z * 0.15915494309189535f;      // 1/(2*pi)
    asm("v_sin_f32 %0, %1" : "=v"(s1) : "v"(zs));
    asm("v_cos_f32 %0, %1" : "=v"(c1) : "v"(zs));
    acc = fmaf(A0, s1, acc);
    acc = fmaf(A1, s1 * c1, acc);
    float t = s1 * s1;
    acc = fmaf(A2 * s1, fmaf(t, -4.f, 3.f), acc);
    return acc;
}

__device__ __forceinline__ void act_pack4_cf(const f32x4& v,
    const float4& S4, const float4& mS4, const float4& A0,
    const float4& A1, const float4& A2, u32x2& hi, u32x2& lo) {
    float x0 = rowdy_cf(v[0], S4.x, mS4.x, A0.x, A1.x, A2.x);
    float x1 = rowdy_cf(v[1], S4.y, mS4.y, A0.y, A1.y, A2.y);
    float x2 = rowdy_cf(v[2], S4.z, mS4.z, A0.z, A1.z, A2.z);
    float x3 = rowdy_cf(v[3], S4.w, mS4.w, A0.w, A1.w, A2.w);
    uint32_t d0 = cvt_pk_bf16(x0, x1);
    uint32_t d1 = cvt_pk_bf16(x2, x3);
    float r0 = x0 - __uint_as_float(d0 << 16);
    float r1 = x1 - __uint_as_float(d0 & 0xFFFF0000u);
    float r2 = x2 - __uint_as_float(d1 << 16);
    float r3 = x3 - __uint_as_float(d1 & 0xFFFF0000u);
    hi = (u32x2){d0, d1};
    lo = (u32x2){cvt_pk_bf16(r0, r1), cvt_pk_bf16(r2, r3)};
}

// ---------- fused prep (blocks 0..39) + branch tower (blocks 40..55) ----------
__global__ void prep_branch(
    const float* __restrict__ tWr,
    const float* __restrict__ params,
    const float* __restrict__ bW0, const float* __restrict__ bWr,
    const float* __restrict__ bb,  const float* __restrict__ bWout,
    const float* __restrict__ bbout,
    const float* __restrict__ fW,  const float* __restrict__ fb,
    const float* __restrict__ ra,
    uint16_t* __restrict__ WfH, uint16_t* __restrict__ WfL,
    float* __restrict__ CF, float* __restrict__ M, float* __restrict__ c0)
{
    const int blk = blockIdx.x;
    if (blk < 40) {
        // ---- weight prep: split + A-fragment reorder ----
        const int layer = blk >> 3;
        const int wv    = (blk >> 1) & 3;
        const int jf    = blk & 1;
        const int t     = threadIdx.x;         // 256 = (ks, lane)
        const int ks    = t >> 6;
        const int ln    = t & 63;
        const int j     = wv * 32 + jf * 16 + (ln & 15);
        const int kbase = ks * 32 + (ln >> 4) * 8;
        uint16_t hi[8], lo[8];
        #pragma unroll
        for (int e = 0; e < 8; ++e) {
            float w = tWr[((size_t)layer * H_ + kbase + e) * H_ + j];
            uint16_t h = f2bf(w);
            hi[e] = h;
            lo[e] = f2bf(w - bf2f(h));
        }
        size_t dst = ((size_t)((((layer * 4 + wv) * 2 + jf) * 4 + ks) * 64 + ln)) * 8;
        #pragma unroll
        for (int e = 0; e < 8; ++e) { WfH[dst + e] = hi[e]; WfL[dst + e] = lo[e]; }
        return;
    }

    // ---- branch tower (both 128-halves duplicate the same work) ----
    const int b = blk - 40;
    const int j = threadIdx.x & 127;
    __shared__ float h[H_];
    __shared__ float zl[O_][H_];

    float z = bb[j];
    #pragma unroll
    for (int k = 0; k < PDIM_; ++k)
        z = fmaf(params[b * PDIM_ + k], bW0[k * H_ + j], z);
    float hv = tanhf(z);
    float srun = hv;
    h[j] = hv;
    {
        float* cf = CF + (size_t)(0 * B_ + b) * 4 * H_;
        cf[0 * H_ + j] = srun;
        cf[1 * H_ + j] = ra[(0 * K_ + 0) * H_ + j] * srun;
        cf[2 * H_ + j] = 2.f * ra[(0 * K_ + 1) * H_ + j] * srun;
        cf[3 * H_ + j] = ra[(0 * K_ + 2) * H_ + j] * srun;
    }

    for (int i = 1; i < L_; ++i) {
        __syncthreads();
        const float* W = bWr + (size_t)(i - 1) * H_ * H_;
        float zz = bb[i * H_ + j];
        for (int k = 0; k < H_; ++k)
            zz = fmaf(h[k], W[k * H_ + j], zz);
        __syncthreads();
        hv = tanhf(zz);
        h[j] = hv;
        srun += hv;
        float* cf = CF + (size_t)(i * B_ + b) * 4 * H_;
        cf[0 * H_ + j] = srun;
        cf[1 * H_ + j] = ra[(i * K_ + 0) * H_ + j] * srun;
        cf[2 * H_ + j] = 2.f * ra[(i * K_ + 1) * H_ + j] * srun;
        cf[3 * H_ + j] = ra[(i * K_ + 2) * H_ + j] * srun;
    }
    __syncthreads();

    #pragma unroll
    for (int o = 0; o < O_; ++o) {
        float acc = bbout[o * H_ + j];
        for (int k = 0; k < H_; ++k)
            acc = fmaf(h[k], bWout[(size_t)k * (H_ * O_) + o * H_ + j], acc);
        zl[o][j] = acc;
    }
    __syncthreads();

    float m[O_] = {0.f, 0.f, 0.f, 0.f};
    for (int hh = 0; hh < H_; ++hh) {
        float w = fW[j * H_ + hh];
        #pragma unroll
        for (int o = 0; o < O_; ++o)
            m[o] = fmaf(w, zl[o][hh], m[o]);
    }
    #pragma unroll
    for (int o = 0; o < O_; ++o)
        M[((size_t)b * H_ + j) * O_ + o] = m[o];

    if (j < O_) {
        float acc = 0.f;
        for (int hh = 0; hh < H_; ++hh)
            acc = fmaf(fb[hh], zl[j][hh], acc);
        c0[b * O_ + j] = acc;
    }
}

// ---------- trunk: double-buffered frag LDS, jf-split half-passes ----------
// Peak live set per half-pass: acc[4] (16) + transient A/B frags (~16) ->
// no spill. (256,2): VGPR cap 256; LDS (64 KB) caps occupancy at 2 blk/CU.
__global__ __launch_bounds__(256, 2) void trunk_mfma(
    const float* __restrict__ coords, const float* __restrict__ sdf,
    const float* __restrict__ tW0,    const float* __restrict__ tb,
    const float* __restrict__ CF,     const float* __restrict__ M,
    const float* __restrict__ c0,
    const uint16_t* __restrict__ WfH, const uint16_t* __restrict__ WfL,
    float* __restrict__ out)
{
    __shared__ __align__(16) uint16_t Xf[2][4 * 4 * 2 * 64 * 8];   // 2 x 32 KiB

    const int blk  = blockIdx.x;
    const int b    = blk / TILES_PER_B;
    const int tile = blk % TILES_PER_B;
    const int p0   = tile * TPTS;
    const int t    = threadIdx.x;

    // ---- layer 0: (coords,sdf) -> H, rowdy, write frag layout into buf 0 ----
    {
        const int p   = t >> 2;
        const int q   = t & 3;          // j-slab q -> ks'=q
        const int pf  = p >> 4;
        const int p15 = p & 15;
        int pg = p0 + p;
        int pc = pg < NPTS_ ? pg : NPTS_ - 1;
        size_t gp = (size_t)b * NPTS_ + pc;
        float in0 = coords[gp * 3 + 0], in1 = coords[gp * 3 + 1];
        float in2 = coords[gp * 3 + 2], in3 = sdf[gp];
        const float* cf0 = CF + (size_t)(0 * B_ + b) * 4 * H_;
        #pragma unroll
        for (int m = 0; m < 4; ++m) {
            const int jo = q * 32 + m * 8;
            u32x2 hiA, loA, hiB, loB;
            #pragma unroll
            for (int half = 0; half < 2; ++half) {
                const int j = jo + half * 4;
                float4 w0 = *(const float4*)(tW0 + 0 * H_ + j);
                float4 w1 = *(const float4*)(tW0 + 1 * H_ + j);
                float4 w2 = *(const float4*)(tW0 + 2 * H_ + j);
                float4 w3 = *(const float4*)(tW0 + 3 * H_ + j);
                float4 bv = *(const float4*)(tb + j);
                float4 S4 = *(const float4*)(cf0 + 0 * H_ + j);
                float4 A0 = *(const float4*)(cf0 + 1 * H_ + j);
                float4 A1 = *(const float4*)(cf0 + 2 * H_ + j);
                float4 A2 = *(const float4*)(cf0 + 3 * H_ + j);
                float4 mS4 = make_float4(-2.f * S4.x, -2.f * S4.y, -2.f * S4.z, -2.f * S4.w);
                f32x4 zv;
                zv[0] = fmaf(in3, w3.x, fmaf(in2, w2.x, fmaf(in1, w1.x, fmaf(in0, w0.x, bv.x))));
                zv[1] = fmaf(in3, w3.y, fmaf(in2, w2.y, fmaf(in1, w1.y, fmaf(in0, w0.y, bv.y))));
                zv[2] = fmaf(in3, w3.z, fmaf(in2, w2.z, fmaf(in1, w1.z, fmaf(in0, w0.z, bv.z))));
                zv[3] = fmaf(in3, w3.w, fmaf(in2, w2.w, fmaf(in1, w1.w, fmaf(in0, w0.w, bv.w))));
                if (half == 0) act_pack4_cf(zv, S4, mS4, A0, A1, A2, hiA, loA);
                else           act_pack4_cf(zv, S4, mS4, A0, A1, A2, hiB, loB);
            }
            const int lane = m * 16 + p15;
            *(u32x4*)(&Xf[0][FRAG(q, pf, 0, lane)]) = (u32x4){hiA[0], hiA[1], hiB[0], hiB[1]};
            *(u32x4*)(&Xf[0][FRAG(q, pf, 1, lane)]) = (u32x4){loA[0], loA[1], loB[0], loB[1]};
        }
    }
    __syncthreads();

    // ---- layers 1..5 via MFMA: read buf[(layer-1)&1], write buf[layer&1] ----
    const int ln    = t & 63;
    const int wv    = t >> 6;          // wave -> j-slice of 32 (= ks' it produces)
    const int l15   = ln & 15;
    const int l4    = ln >> 4;
    const int jbase = wv * 32;
    const int l4p   = l4 >> 1;
    const int eoff  = (l4 & 1) * 4;

    for (int layer = 1; layer < L_; ++layer) {
        const uint16_t* Xc = Xf[(layer - 1) & 1];
        uint16_t*       Xn = Xf[layer & 1];
        const size_t wbase = ((size_t)((layer - 1) * 4 + wv)) * 4096;  // 2*4*64*8
        const uint16_t* WH = WfH + wbase;
        const uint16_t* WL = WfL + wbase;
        const float*    cf = CF + (size_t)(layer * B_ + b) * 4 * H_;

        #pragma unroll 1
        for (int jf = 0; jf < 2; ++jf) {
            const int j4 = jbase + jf * 16 + l4 * 4;
            f32x4 acc[4];
            {
                float4 bv = *(const float4*)(tb + layer * H_ + j4);
                #pragma unroll
                for (int pf = 0; pf < 4; ++pf)
                    acc[pf] = (f32x4){bv.x, bv.y, bv.z, bv.w};
            }
            #pragma unroll
            for (int ks = 0; ks < 4; ++ks) {
                short8 aH = *(const short8*)(WH + WFRAG(jf, ks, ln));
                short8 aL = *(const short8*)(WL + WFRAG(jf, ks, ln));
                #pragma unroll
                for (int pf = 0; pf < 4; ++pf) {
                    short8 bH = *(const short8*)(&Xc[FRAG(ks, pf, 0, ln)]);
                    short8 bL = *(const short8*)(&Xc[FRAG(ks, pf, 1, ln)]);
                    acc[pf] = __builtin_amdgcn_mfma_f32_16x16x32_bf16(aH, bH, acc[pf], 0, 0, 0);
                    acc[pf] = __builtin_amdgcn_mfma_f32_16x16x32_bf16(aH, bL, acc[pf], 0, 0, 0);
                    acc[pf] = __builtin_amdgcn_mfma_f32_16x16x32_bf16(aL, bH, acc[pf], 0, 0, 0);
                }
            }
            // act + write into next buffer (wave's own ks'=wv slice)
            float4 S4 = *(const float4*)(cf + 0 * H_ + j4);
            float4 A0 = *(const float4*)(cf + 1 * H_ + j4);
            float4 A1 = *(const float4*)(cf + 2 * H_ + j4);
            float4 A2 = *(const float4*)(cf + 3 * H_ + j4);
            float4 mS4 = make_float4(-2.f * S4.x, -2.f * S4.y, -2.f * S4.z, -2.f * S4.w);
            const int lanep = (jf * 2 + l4p) * 16 + l15;
            #pragma unroll
            for (int pf = 0; pf < 4; ++pf) {
                u32x2 hi, lo;
                act_pack4_cf(acc[pf], S4, mS4, A0, A1, A2, hi, lo);
                *(u32x2*)(&Xn[FRAG(wv, pf, 0, lanep) + eoff]) = hi;
                *(u32x2*)(&Xn[FRAG(wv, pf, 1, lanep) + eoff]) = lo;
            }
        }
        __syncthreads();   // layer writes visible; all reads of Xc were pre-barrier
    }

    // ---- fused final layer + O-contraction (reads buf[(L-1)&1] = buf 1) ----
    {
        const uint16_t* Xl = Xf[(L_ - 1) & 1];
        const int p   = t >> 2;
        const int o   = t & 3;
        const int pf  = p >> 4;
        const int p15 = p & 15;
        float acc = c0[b * O_ + o];
        const float* Mb = M + (size_t)b * H_ * O_;
        #pragma unroll
        for (int ks = 0; ks < 4; ++ks) {
            #pragma unroll
            for (int m = 0; m < 4; ++m) {
                const int lane = m * 16 + p15;
                short8 h8 = *(const short8*)(&Xl[FRAG(ks, pf, 0, lane)]);
                short8 l8 = *(const short8*)(&Xl[FRAG(ks, pf, 1, lane)]);
                const int kb = ks * 32 + m * 8;
                #pragma unroll
                for (int e = 0; e < 8; ++e) {
                    float xv = bf2f((uint16_t)h8[e]) + bf2f((uint16_t)l8[e]);
                    acc = fmaf(xv, Mb[(kb + e) * O_ + o], acc);
                }
            }
        }
        int gp = p0 + p;
        if (gp < NPTS_)
            out[((size_t)b * NPTS_ + gp) * O_ + o] = acc;
    }
}

extern "C" void kernel_launch(void* const* d_in, const int* in_sizes, int n_in,
                              void* d_out, int out_size, void* d_ws, size_t ws_size,
                              hipStream_t stream) {
    const float* coords  = (const float*)d_in[0];
    const float* sdf     = (const float*)d_in[1];
    const float* params  = (const float*)d_in[2];
    const float* bW0     = (const float*)d_in[3];
    const float* bWr     = (const float*)d_in[4];
    const float* bb      = (const float*)d_in[5];
    const float* bWout   = (const float*)d_in[6];
    const float* bbout   = (const float*)d_in[7];
    const float* tW0     = (const float*)d_in[8];
    const float* tWr     = (const float*)d_in[9];
    const float* tb      = (const float*)d_in[10];
    const float* ra      = (const float*)d_in[11];
    const float* fW      = (const float*)d_in[12];
    const float* fb      = (const float*)d_in[13];
    float* out = (float*)d_out;

    float* CF = (float*)d_ws;                           // 6*16*4*128 = 49152 floats
    float* M  = CF + (size_t)L_ * B_ * 4 * H_;          // 16*128*4
    float* c0 = M + (size_t)B_ * H_ * O_;               // 64
    uint16_t* WfH = (uint16_t*)(c0 + B_ * O_);          // 5*128*128 ushort
    uint16_t* WfL = WfH + (size_t)(L_ - 1) * H_ * H_;

    prep_branch<<<dim3(40 + B_), dim3(256), 0, stream>>>(
        tWr, params, bW0, bWr, bb, bWout, bbout, fW, fb, ra,
        WfH, WfL, CF, M, c0);
    trunk_mfma<<<dim3(B_ * TILES_PER_B), dim3(256), 0, stream>>>(
        coords, sdf, tW0, tb, CF, M, c0, WfH, WfL, out);
}

// Round 10
// 476.635 us; speedup vs baseline: 1.3970x; 1.0225x over previous
//
#include <hip/hip_runtime.h>
#include <hip/hip_bf16.h>
#include <stdint.h>

#define B_    16
#define NPTS_ 20000
#define H_    128
#define O_    4
#define L_    6
#define PDIM_ 8
#define K_    3

#define PTS_PER_WAVE 16
#define NTILES (NPTS_ / PTS_PER_WAVE)          // 1250 (exact)
#define NBLOCKS (B_ * NTILES / 4)              // 5000 blocks x 4 waves

typedef __attribute__((ext_vector_type(8))) short short8;
typedef __attribute__((ext_vector_type(4))) float f32x4;
typedef __attribute__((ext_vector_type(2))) uint32_t u32x2;
typedef __attribute__((ext_vector_type(4))) uint32_t u32x4;

// XOR-swizzled slot for the per-wave pk scratch: 16B per lane-slot,
// swizzle bits 4-5 with bits 7-8 to break 4p-bank alignment.
#define XSL(lam) ((uint32_t)(((lam)*16) ^ (((((lam)>>3)&3))<<4)))

__device__ __forceinline__ uint32_t cvt_pk_bf16(float a, float b) {
    uint32_t d;
    asm("v_cvt_pk_bf16_f32 %0, %1, %2" : "=v"(d) : "v"(a), "v"(b));
    return d;
}
__device__ __forceinline__ float bf2f(uint16_t h) {
    return __uint_as_float(((uint32_t)h) << 16);
}
__device__ __forceinline__ uint16_t f2bf(float x) {
    uint32_t u = __float_as_uint(x);
    uint32_t r = u + 0x7FFFu + ((u >> 16) & 1u);
    return (uint16_t)(r >> 16);
}
__device__ __forceinline__ short8 mk8(uint32_t a, uint32_t b, uint32_t c, uint32_t d) {
    u32x4 t = (u32x4){a, b, c, d};
    return __builtin_bit_cast(short8, t);
}
__device__ __forceinline__ float bperm_f(int byteaddr, float v) {
    return __int_as_float(__builtin_amdgcn_ds_bpermute(byteaddr, __float_as_int(v)));
}

// x = S*tanh(z) + (a0*S)sin z + (2a1*S)sin z cos z + (a2*S)(3 sin z - 4 sin^3 z)
__device__ __forceinline__ float rowdy_cf(float z, float S, float mS,
                                          float A0, float A1, float A2) {
    float e, s1, c1;
    float zl = z * 2.8853900817779268f;       // 2*log2(e)
    asm("v_exp_f32 %0, %1" : "=v"(e) : "v"(zl));
    float r = __builtin_amdgcn_rcpf(e + 1.f);
    float acc = fmaf(mS, r, S);               // S*tanh(z)
    float zs = z * 0.15915494309189535f;      // 1/(2*pi)
    asm("v_sin_f32 %0, %1" : "=v"(s1) : "v"(zs));
    asm("v_cos_f32 %0, %1" : "=v"(c1) : "v"(zs));
    acc = fmaf(A0, s1, acc);
    acc = fmaf(A1, s1 * c1, acc);
    float t = s1 * s1;
    acc = fmaf(A2 * s1, fmaf(t, -4.f, 3.f), acc);
    return acc;
}

__device__ __forceinline__ void act_pack4_cf(const f32x4& v,
    const float4& S4, const float4& mS4, const float4& A0,
    const float4& A1, const float4& A2, u32x2& hi, u32x2& lo) {
    float x0 = rowdy_cf(v[0], S4.x, mS4.x, A0.x, A1.x, A2.x);
    float x1 = rowdy_cf(v[1], S4.y, mS4.y, A0.y, A1.y, A2.y);
    float x2 = rowdy_cf(v[2], S4.z, mS4.z, A0.z, A1.z, A2.z);
    float x3 = rowdy_cf(v[3], S4.w, mS4.w, A0.w, A1.w, A2.w);
    uint32_t d0 = cvt_pk_bf16(x0, x1);
    uint32_t d1 = cvt_pk_bf16(x2, x3);
    float r0 = x0 - __uint_as_float(d0 << 16);
    float r1 = x1 - __uint_as_float(d0 & 0xFFFF0000u);
    float r2 = x2 - __uint_as_float(d1 << 16);
    float r3 = x3 - __uint_as_float(d1 & 0xFFFF0000u);
    hi = (u32x2){d0, d1};
    lo = (u32x2){cvt_pk_bf16(r0, r1), cvt_pk_bf16(r2, r3)};
}

// ---------- fused prep (blocks 0..39) + branch tower (blocks 40..55) ----------
// Wf (ushort idx): slab (layer*8 + JF), frag ks: ((layer*8+JF)*4+ks)*512 + ln*8
// element: j = JF*16 + (ln&15), k = ks*32 + (ln>>4)*8 + e
__global__ void prep_branch(
    const float* __restrict__ tWr,
    const float* __restrict__ params,
    const float* __restrict__ bW0, const float* __restrict__ bWr,
    const float* __restrict__ bb,  const float* __restrict__ bWout,
    const float* __restrict__ bbout,
    const float* __restrict__ fW,  const float* __restrict__ fb,
    const float* __restrict__ ra,
    uint16_t* __restrict__ WfH, uint16_t* __restrict__ WfL,
    float* __restrict__ CF, float* __restrict__ M, float* __restrict__ c0)
{
    const int blk = blockIdx.x;
    if (blk < 40) {
        const int layer = blk >> 3;
        const int JF    = blk & 7;
        const int t     = threadIdx.x;         // 256 = (ks, lane)
        const int ks    = t >> 6;
        const int ln    = t & 63;
        const int j     = JF * 16 + (ln & 15);
        const int kbase = ks * 32 + (ln >> 4) * 8;
        uint16_t hi[8], lo[8];
        #pragma unroll
        for (int e = 0; e < 8; ++e) {
            float w = tWr[((size_t)layer * H_ + kbase + e) * H_ + j];
            uint16_t h = f2bf(w);
            hi[e] = h;
            lo[e] = f2bf(w - bf2f(h));
        }
        size_t dst = ((size_t)((layer * 8 + JF) * 4 + ks) * 64 + ln) * 8;
        #pragma unroll
        for (int e = 0; e < 8; ++e) { WfH[dst + e] = hi[e]; WfL[dst + e] = lo[e]; }
        return;
    }

    const int b = blk - 40;
    const int j = threadIdx.x & 127;
    __shared__ float h[H_];
    __shared__ float zl[O_][H_];

    float z = bb[j];
    #pragma unroll
    for (int k = 0; k < PDIM_; ++k)
        z = fmaf(params[b * PDIM_ + k], bW0[k * H_ + j], z);
    float hv = tanhf(z);
    float srun = hv;
    h[j] = hv;
    {
        float* cf = CF + (size_t)(0 * B_ + b) * 4 * H_;
        cf[0 * H_ + j] = srun;
        cf[1 * H_ + j] = ra[(0 * K_ + 0) * H_ + j] * srun;
        cf[2 * H_ + j] = 2.f * ra[(0 * K_ + 1) * H_ + j] * srun;
        cf[3 * H_ + j] = ra[(0 * K_ + 2) * H_ + j] * srun;
    }

    for (int i = 1; i < L_; ++i) {
        __syncthreads();
        const float* W = bWr + (size_t)(i - 1) * H_ * H_;
        float zz = bb[i * H_ + j];
        for (int k = 0; k < H_; ++k)
            zz = fmaf(h[k], W[k * H_ + j], zz);
        __syncthreads();
        hv = tanhf(zz);
        h[j] = hv;
        srun += hv;
        float* cf = CF + (size_t)(i * B_ + b) * 4 * H_;
        cf[0 * H_ + j] = srun;
        cf[1 * H_ + j] = ra[(i * K_ + 0) * H_ + j] * srun;
        cf[2 * H_ + j] = 2.f * ra[(i * K_ + 1) * H_ + j] * srun;
        cf[3 * H_ + j] = ra[(i * K_ + 2) * H_ + j] * srun;
    }
    __syncthreads();

    #pragma unroll
    for (int o = 0; o < O_; ++o) {
        float acc = bbout[o * H_ + j];
        for (int k = 0; k < H_; ++k)
            acc = fmaf(h[k], bWout[(size_t)k * (H_ * O_) + o * H_ + j], acc);
        zl[o][j] = acc;
    }
    __syncthreads();

    float m[O_] = {0.f, 0.f, 0.f, 0.f};
    for (int hh = 0; hh < H_; ++hh) {
        float w = fW[j * H_ + hh];
        #pragma unroll
        for (int o = 0; o < O_; ++o)
            m[o] = fmaf(w, zl[o][hh], m[o]);
    }
    #pragma unroll
    for (int o = 0; o < O_; ++o)
        M[((size_t)b * H_ + j) * O_ + o] = m[o];

    if (j < O_) {
        float acc = 0.f;
        for (int hh = 0; hh < H_; ++hh)
            acc = fmaf(fb[hh], zl[j][hh], acc);
        c0[b * O_ + j] = acc;
    }
}

// ---------- trunk: wave-resident X, barrier-free ----------
// Each wave owns 16 points x all 128 j. acc = 8 x f32x4 (D[j][p]).
// Layer-to-layer repack (D rows granularity-4 -> B k granularity-8) goes
// through an 8KB/wave LDS scratch, intra-wave only (LDS ops are in-order
// per wave -> no barriers anywhere). W streams as A-frags from global (L1/L2).
__global__ __launch_bounds__(256, 4) void trunk_mfma(
    const float* __restrict__ coords, const float* __restrict__ sdf,
    const float* __restrict__ tW0,    const float* __restrict__ tb,
    const float* __restrict__ CF,     const float* __restrict__ M,
    const float* __restrict__ c0,
    const uint16_t* __restrict__ WfH, const uint16_t* __restrict__ WfL,
    float* __restrict__ out)
{
    __shared__ __align__(16) uint8_t XPK[4][8192];   // 32 KiB/block

    const int t   = threadIdx.x;
    const int wv  = t >> 6;
    const int l   = t & 63;
    const int gid = blockIdx.x * 4 + wv;
    const int b    = gid / NTILES;
    const int tile = gid % NTILES;
    const int p0   = tile * PTS_PER_WAVE;
    const int m    = l >> 4;
    const int p15  = l & 15;
    const int j4b  = m * 4;                 // j4 = JF*16 + m*4

    uint8_t* lb = &XPK[wv][0];
    // writer slot: lane l, frag JF at lb + JF*1024 + XSL(l)
    uint8_t* pW = lb + XSL(l);
    // reader slots: frag f = 2ks + (m>>1); lamA = 2(m&1)*16 + p; lamB = lamA+16
    const int lamA = ((l & 16) << 1) | p15;
    uint8_t* pA = lb + (uint32_t)((m >> 1) * 1024) + XSL(lamA);
    uint8_t* pB = lb + (uint32_t)((m >> 1) * 1024) + XSL(lamA + 16);

    // ---- layer 0: (coords,sdf) -> 128, rowdy, pack -> scratch ----
    {
        const size_t gp = (size_t)b * NPTS_ + p0 + p15;
        float in0 = coords[gp * 3 + 0], in1 = coords[gp * 3 + 1];
        float in2 = coords[gp * 3 + 2], in3 = sdf[gp];
        const float* cf0 = CF + (size_t)b * 4 * H_;
        #pragma unroll
        for (int JF = 0; JF < 8; ++JF) {
            const int j4 = JF * 16 + j4b;
            float4 w0 = *(const float4*)(tW0 + 0 * H_ + j4);
            float4 w1 = *(const float4*)(tW0 + 1 * H_ + j4);
            float4 w2 = *(const float4*)(tW0 + 2 * H_ + j4);
            float4 w3 = *(const float4*)(tW0 + 3 * H_ + j4);
            float4 bv = *(const float4*)(tb + j4);
            f32x4 zv;
            zv[0] = fmaf(in3, w3.x, fmaf(in2, w2.x, fmaf(in1, w1.x, fmaf(in0, w0.x, bv.x))));
            zv[1] = fmaf(in3, w3.y, fmaf(in2, w2.y, fmaf(in1, w1.y, fmaf(in0, w0.y, bv.y))));
            zv[2] = fmaf(in3, w3.z, fmaf(in2, w2.z, fmaf(in1, w1.z, fmaf(in0, w0.z, bv.z))));
            zv[3] = fmaf(in3, w3.w, fmaf(in2, w2.w, fmaf(in1, w1.w, fmaf(in0, w0.w, bv.w))));
            float4 S4 = *(const float4*)(cf0 + 0 * H_ + j4);
            float4 A0 = *(const float4*)(cf0 + 1 * H_ + j4);
            float4 A1 = *(const float4*)(cf0 + 2 * H_ + j4);
            float4 A2 = *(const float4*)(cf0 + 3 * H_ + j4);
            float4 mS4 = make_float4(-2.f * S4.x, -2.f * S4.y, -2.f * S4.z, -2.f * S4.w);
            u32x2 hi, lo;
            act_pack4_cf(zv, S4, mS4, A0, A1, A2, hi, lo);
            *(u32x4*)(pW + JF * 1024) = (u32x4){hi[0], hi[1], lo[0], lo[1]};
        }
    }

    // ---- layers 1..5: MFMA from scratch-B + global-A, act, repack ----
    const uint16_t* WH = WfH;
    const uint16_t* WL = WfL;
    #pragma unroll 1
    for (int layer = 1; layer <= 5; ++layer) {
        f32x4 acc[8];
        #pragma unroll
        for (int JF = 0; JF < 8; ++JF) {
            float4 bv = *(const float4*)(tb + layer * H_ + JF * 16 + j4b);
            acc[JF] = (f32x4){bv.x, bv.y, bv.z, bv.w};
        }
        #pragma unroll
        for (int ks = 0; ks < 4; ++ks) {
            u32x4 RA = *(const u32x4*)(pA + ks * 2048);
            u32x4 RB = *(const u32x4*)(pB + ks * 2048);
            short8 bH = mk8(RA.x, RA.y, RB.x, RB.y);
            short8 bL = mk8(RA.z, RA.w, RB.z, RB.w);
            #pragma unroll
            for (int JF = 0; JF < 8; ++JF) {
                const size_t off = (size_t)((JF * 4 + ks) * 512) + l * 8;
                short8 aH = *(const short8*)(WH + off);
                short8 aL = *(const short8*)(WL + off);
                acc[JF] = __builtin_amdgcn_mfma_f32_16x16x32_bf16(aH, bH, acc[JF], 0, 0, 0);
                acc[JF] = __builtin_amdgcn_mfma_f32_16x16x32_bf16(aH, bL, acc[JF], 0, 0, 0);
                acc[JF] = __builtin_amdgcn_mfma_f32_16x16x32_bf16(aL, bH, acc[JF], 0, 0, 0);
            }
        }
        const float* cf = CF + (size_t)(layer * B_ + b) * 4 * H_;
        #pragma unroll
        for (int JF = 0; JF < 8; ++JF) {
            const int j4 = JF * 16 + j4b;
            float4 S4 = *(const float4*)(cf + 0 * H_ + j4);
            float4 A0 = *(const float4*)(cf + 1 * H_ + j4);
            float4 A1 = *(const float4*)(cf + 2 * H_ + j4);
            float4 A2 = *(const float4*)(cf + 3 * H_ + j4);
            float4 mS4 = make_float4(-2.f * S4.x, -2.f * S4.y, -2.f * S4.z, -2.f * S4.w);
            u32x2 hi, lo;
            act_pack4_cf(acc[JF], S4, mS4, A0, A1, A2, hi, lo);
            *(u32x4*)(pW + JF * 1024) = (u32x4){hi[0], hi[1], lo[0], lo[1]};
        }
        WH += 8 * 2048;   // next layer slab (shorts)
        WL += 8 * 2048;
    }

    // ---- final: out[p][o] = c0[o] + sum_k x[k][p] * M[k][o] ----
    {
        f32x4 part = (f32x4){0.f, 0.f, 0.f, 0.f};
        const float* Mb = M + (size_t)b * H_ * O_;
        #pragma unroll
        for (int ks = 0; ks < 4; ++ks) {
            u32x4 RA = *(const u32x4*)(pA + ks * 2048);
            u32x4 RB = *(const u32x4*)(pB + ks * 2048);
            const int kb = ks * 32 + m * 8;
            uint32_t hw[4] = {RA.x, RA.y, RB.x, RB.y};
            uint32_t lw[4] = {RA.z, RA.w, RB.z, RB.w};
            #pragma unroll
            for (int q = 0; q < 4; ++q) {
                float xe = __uint_as_float(hw[q] << 16) + __uint_as_float(lw[q] << 16);
                float xo = __uint_as_float(hw[q] & 0xFFFF0000u) + __uint_as_float(lw[q] & 0xFFFF0000u);
                float4 Me = *(const float4*)(Mb + (size_t)(kb + 2 * q) * O_);
                float4 Mo = *(const float4*)(Mb + (size_t)(kb + 2 * q + 1) * O_);
                part[0] = fmaf(xe, Me.x, part[0]); part[0] = fmaf(xo, Mo.x, part[0]);
                part[1] = fmaf(xe, Me.y, part[1]); part[1] = fmaf(xo, Mo.y, part[1]);
                part[2] = fmaf(xe, Me.z, part[2]); part[2] = fmaf(xo, Mo.z, part[2]);
                part[3] = fmaf(xe, Me.w, part[3]); part[3] = fmaf(xo, Mo.w, part[3]);
            }
        }
        // butterfly reduce over the 4 m-groups (same p)
        const int a16 = (l ^ 16) << 2;
        const int a32 = (l ^ 32) << 2;
        #pragma unroll
        for (int i = 0; i < 4; ++i) {
            float v = part[i];
            v += bperm_f(a16, v);
            v += bperm_f(a32, v);
            part[i] = v;
        }
        float4 cv = *(const float4*)(c0 + b * O_);
        if (l < 16) {
            float4 o4 = make_float4(part[0] + cv.x, part[1] + cv.y,
                                    part[2] + cv.z, part[3] + cv.w);
            *(float4*)(out + ((size_t)b * NPTS_ + p0 + l) * O_) = o4;
        }
    }
}

extern "C" void kernel_launch(void* const* d_in, const int* in_sizes, int n_in,
                              void* d_out, int out_size, void* d_ws, size_t ws_size,
                              hipStream_t stream) {
    const float* coords  = (const float*)d_in[0];
    const float* sdf     = (const float*)d_in[1];
    const float* params  = (const float*)d_in[2];
    const float* bW0     = (const float*)d_in[3];
    const float* bWr     = (const float*)d_in[4];
    const float* bb      = (const float*)d_in[5];
    const float* bWout   = (const float*)d_in[6];
    const float* bbout   = (const float*)d_in[7];
    const float* tW0     = (const float*)d_in[8];
    const float* tWr     = (const float*)d_in[9];
    const float* tb      = (const float*)d_in[10];
    const float* ra      = (const float*)d_in[11];
    const float* fW      = (const float*)d_in[12];
    const float* fb      = (const float*)d_in[13];
    float* out = (float*)d_out;

    float* CF = (float*)d_ws;                           // 6*16*4*128 floats
    float* M  = CF + (size_t)L_ * B_ * 4 * H_;          // 16*128*4
    float* c0 = M + (size_t)B_ * H_ * O_;               // 64
    uint16_t* WfH = (uint16_t*)(c0 + B_ * O_);          // 5*128*128 ushort
    uint16_t* WfL = WfH + (size_t)(L_ - 1) * H_ * H_;

    prep_branch<<<dim3(40 + B_), dim3(256), 0, stream>>>(
        tWr, params, bW0, bWr, bb, bWout, bbout, fW, fb, ra,
        WfH, WfL, CF, M, c0);
    trunk_mfma<<<dim3(NBLOCKS), dim3(256), 0, stream>>>(
        coords, sdf, tW0, tb, CF, M, c0, WfH, WfL, out);
}